// Round 2
// baseline (110.192 us; speedup 1.0000x reference)
//
#include <hip/hip_runtime.h>
#include <math.h>

#define BATCH 128
#define FEAT  1024
#define CLS   500
#define HID   512
#define SPL   8          // split-K factor

// ---------------------------------------------------------------------------
// Stage 1: fused split-K GEMM for both halves, register-prefetch pipelined.
//   imgP[z][m][n]  = sum_{k in split z} img[m][k]  * W1[n][k]
//   attrP[z][m][n] = sum_{k in split z} attr[m][k] * W1[n][FEAT+k]
// grid = (8 n-tiles, 2 img + 8 attr m-tiles, SPL) = 640 blocks.
// ---------------------------------------------------------------------------
constexpr int BM = 64, BN = 64, BK = 16;

__global__ __launch_bounds__(256) void gemm_bt_splitk(
    const float* __restrict__ img, const float* __restrict__ attr,
    const float* __restrict__ W1,
    float* __restrict__ imgP, float* __restrict__ attrP)
{
    __shared__ float As[BK][BM + 4];
    __shared__ float Bs[BK][BN + 4];

    const int t  = threadIdx.x;
    const int z  = blockIdx.z;
    const int n0 = blockIdx.x * BN;

    const float* A;
    float* P;
    int M, boff, m0;
    if (blockIdx.y < 2) {
        A = img;  P = imgP;  M = BATCH; boff = 0;
        m0 = blockIdx.y * BM;
    } else {
        A = attr; P = attrP; M = CLS;  boff = FEAT;
        m0 = (blockIdx.y - 2) * BM;
    }

    const int K    = FEAT;
    const int ldb  = 2 * FEAT;
    const int Ks   = K / SPL;          // 128
    const int kb   = z * Ks;

    const int lrow = t >> 2;           // 0..63
    const int lk4  = (t & 3) * 4;      // 0,4,8,12

    const int tn = t & 15;
    const int tm = t >> 4;

    const bool aok = (m0 + lrow) < M;
    const float* Arow = A  + (size_t)(m0 + lrow) * K;
    const float* Brow = W1 + (size_t)(n0 + lrow) * ldb + boff;

    // prefetch tile 0 into registers
    float4 av = aok ? *(const float4*)&Arow[kb + lk4]
                    : make_float4(0.f, 0.f, 0.f, 0.f);
    float4 bv = *(const float4*)&Brow[kb + lk4];

    float acc[4][4];
    #pragma unroll
    for (int i = 0; i < 4; ++i)
        #pragma unroll
        for (int j = 0; j < 4; ++j) acc[i][j] = 0.f;

    for (int kt = 0; kt < Ks; kt += BK) {
        // commit staged registers to LDS (transposed)
        As[lk4 + 0][lrow] = av.x;
        As[lk4 + 1][lrow] = av.y;
        As[lk4 + 2][lrow] = av.z;
        As[lk4 + 3][lrow] = av.w;
        Bs[lk4 + 0][lrow] = bv.x;
        Bs[lk4 + 1][lrow] = bv.y;
        Bs[lk4 + 2][lrow] = bv.z;
        Bs[lk4 + 3][lrow] = bv.w;
        __syncthreads();

        // issue next tile's global loads; latency hidden by the FMA block
        if (kt + BK < Ks) {
            av = aok ? *(const float4*)&Arow[kb + kt + BK + lk4]
                     : make_float4(0.f, 0.f, 0.f, 0.f);
            bv = *(const float4*)&Brow[kb + kt + BK + lk4];
        }

        #pragma unroll
        for (int k = 0; k < BK; ++k) {
            const float4 a = *(const float4*)&As[k][tm * 4];
            const float4 b = *(const float4*)&Bs[k][tn * 4];
            acc[0][0] = fmaf(a.x, b.x, acc[0][0]);
            acc[0][1] = fmaf(a.x, b.y, acc[0][1]);
            acc[0][2] = fmaf(a.x, b.z, acc[0][2]);
            acc[0][3] = fmaf(a.x, b.w, acc[0][3]);
            acc[1][0] = fmaf(a.y, b.x, acc[1][0]);
            acc[1][1] = fmaf(a.y, b.y, acc[1][1]);
            acc[1][2] = fmaf(a.y, b.z, acc[1][2]);
            acc[1][3] = fmaf(a.y, b.w, acc[1][3]);
            acc[2][0] = fmaf(a.z, b.x, acc[2][0]);
            acc[2][1] = fmaf(a.z, b.y, acc[2][1]);
            acc[2][2] = fmaf(a.z, b.z, acc[2][2]);
            acc[2][3] = fmaf(a.z, b.w, acc[2][3]);
            acc[3][0] = fmaf(a.w, b.x, acc[3][0]);
            acc[3][1] = fmaf(a.w, b.y, acc[3][1]);
            acc[3][2] = fmaf(a.w, b.z, acc[3][2]);
            acc[3][3] = fmaf(a.w, b.w, acc[3][3]);
        }
        __syncthreads();
    }

    float* Pz = P + (size_t)z * M * HID;
    #pragma unroll
    for (int i = 0; i < 4; ++i) {
        const int m = m0 + tm * 4 + i;
        if (m < M) {
            float4 v = make_float4(acc[i][0], acc[i][1], acc[i][2], acc[i][3]);
            *(float4*)&Pz[(size_t)m * HID + n0 + tn * 4] = v;
        }
    }
}

// ---------------------------------------------------------------------------
// Stage 2: merge split-K partials; fold b1 into the image part.
// ---------------------------------------------------------------------------
__global__ __launch_bounds__(256) void merge_kernel(
    const float* __restrict__ imgP, const float* __restrict__ attrP,
    const float* __restrict__ b1,
    float* __restrict__ imgF, float* __restrict__ attrF)
{
    const int NIMG  = BATCH * HID;   // 65536
    const int NATTR = CLS * HID;     // 256000
    const int idx = blockIdx.x * 256 + threadIdx.x;
    if (idx < NIMG) {
        float s = 0.f;
        #pragma unroll
        for (int zz = 0; zz < SPL; ++zz) s += imgP[zz * NIMG + idx];
        imgF[idx] = s + b1[idx & (HID - 1)];
    } else if (idx < NIMG + NATTR) {
        const int j = idx - NIMG;
        float s = 0.f;
        #pragma unroll
        for (int zz = 0; zz < SPL; ++zz) s += attrP[zz * NATTR + j];
        attrF[j] = s;
    }
}

// ---------------------------------------------------------------------------
// Stage 3: out[b,c] = sigmoid( sum_h relu(u_b[h]+v_c[h]) * w2[h] + b2 )
// One wave per b-row (u, w2 wave-uniform -> scalar loads); 64 classes per
// block staged in LDS as [h4][class] float4 tiles with XOR swizzle so both
// the transpose-write and read phases are bank-conflict-free.
// ---------------------------------------------------------------------------
constexpr int PC = 64;    // classes per block
constexpr int HC = 128;   // h chunk

__global__ __launch_bounds__(256) void pair_kernel(
    const float* __restrict__ imgF, const float* __restrict__ attrF,
    const float* __restrict__ W2, const float* __restrict__ b2,
    float* __restrict__ out)
{
    __shared__ float4 V[(HC / 4) * PC];   // 32 KB

    const int t   = threadIdx.x;
    const int ci  = t & 63;
    const int wid = __builtin_amdgcn_readfirstlane(t >> 6);  // wave id, SGPR
    const int b   = blockIdx.y * 4 + wid;                    // uniform per wave
    const int c0  = blockIdx.x * PC;

    const float* up = imgF + (size_t)b * HID;  // wave-uniform base -> s_load

    float ax = 0.f, ay = 0.f, az = 0.f, aw = 0.f;

    for (int hc = 0; hc < HID; hc += HC) {
        __syncthreads();
        // stage V chunk: 64 rows x 32 float4, coalesced global reads,
        // XOR-swizzled LDS writes (slot = r ^ f4) -> conflict-free phases
        #pragma unroll
        for (int rep = 0; rep < 8; ++rep) {
            const int idx = rep * 256 + t;    // 0..2047
            const int r   = idx >> 5;         // class row 0..63
            const int f4  = idx & 31;         // h-group 0..31
            float4 v = make_float4(0.f, 0.f, 0.f, 0.f);
            if (c0 + r < CLS)
                v = *(const float4*)&attrF[(size_t)(c0 + r) * HID + hc + f4 * 4];
            V[f4 * PC + ((r ^ f4) & 63)] = v;
        }
        __syncthreads();

        #pragma unroll
        for (int h4 = 0; h4 < HC / 4; ++h4) {
            const float4 v = V[h4 * PC + ((ci ^ h4) & 63)];
            const float4 u = *(const float4*)&up[hc + h4 * 4];  // scalar
            const float4 w = *(const float4*)&W2[hc + h4 * 4];  // scalar
            ax = fmaf(fmaxf(u.x + v.x, 0.f), w.x, ax);
            ay = fmaf(fmaxf(u.y + v.y, 0.f), w.y, ay);
            az = fmaf(fmaxf(u.z + v.z, 0.f), w.z, az);
            aw = fmaf(fmaxf(u.w + v.w, 0.f), w.w, aw);
        }
    }

    const int c = c0 + ci;
    if (c < CLS) {
        const float x = (ax + ay) + (az + aw) + b2[0];
        out[(size_t)b * CLS + c] = 1.f / (1.f + __expf(-x));
    }
}

// ---------------------------------------------------------------------------
extern "C" void kernel_launch(void* const* d_in, const int* in_sizes, int n_in,
                              void* d_out, int out_size, void* d_ws, size_t ws_size,
                              hipStream_t stream) {
    const float* img  = (const float*)d_in[0];   // (128, 1024)
    const float* attr = (const float*)d_in[1];   // (500, 1024)
    const float* W1   = (const float*)d_in[2];   // (512, 2048)
    const float* b1   = (const float*)d_in[3];   // (512,)
    const float* W2   = (const float*)d_in[4];   // (1, 512)
    const float* b2   = (const float*)d_in[5];   // (1,)
    float* out = (float*)d_out;                  // (128, 500)

    float* ws    = (float*)d_ws;
    float* imgP  = ws;                                  // SPL*128*512
    float* attrP = imgP  + (size_t)SPL * BATCH * HID;   // SPL*500*512
    float* imgF  = attrP + (size_t)SPL * CLS * HID;     // 128*512
    float* attrF = imgF  + (size_t)BATCH * HID;         // 500*512

    // Stage 1: both GEMMs, split-K=8 -> 8 x 10 x 8 = 640 blocks
    dim3 ggrid(HID / BN, 2 + 8, SPL);
    gemm_bt_splitk<<<ggrid, 256, 0, stream>>>(img, attr, W1, imgP, attrP);

    // Stage 2: merge partials (+b1 on img side)
    const int ntot = BATCH * HID + CLS * HID;           // 321536
    merge_kernel<<<(ntot + 255) / 256, 256, 0, stream>>>(imgP, attrP, b1, imgF, attrF);

    // Stage 3: pair reduction + sigmoid; (8 c-tiles, 32 b-tiles) = 256 blocks
    dim3 pgrid((CLS + PC - 1) / PC, BATCH / 4);
    pair_kernel<<<pgrid, 256, 0, stream>>>(imgF, attrF, W2, b2, out);
}

// Round 3
// 104.213 us; speedup vs baseline: 1.0574x; 1.0574x over previous
//
#include <hip/hip_runtime.h>
#include <math.h>

#define BATCH 128
#define FEAT  1024
#define CLS   500
#define HID   512
#define SPL   8          // split-K factor

typedef short s16x8 __attribute__((ext_vector_type(8)));
typedef float f32x4 __attribute__((ext_vector_type(4)));

// round-half-up fp32->bf16 pair pack: 2x v_add_u32 + 1x v_perm_b32
__device__ inline unsigned pkbf(float x, float y) {
    unsigned ux = __float_as_uint(x) + 0x8000u;
    unsigned uy = __float_as_uint(y) + 0x8000u;
    // D = bf16(x) | bf16(y)<<16 : bytes = x.b2, x.b3, y.b2, y.b3
    return __builtin_amdgcn_perm(uy, ux, 0x07060302u);
}

// ---------------------------------------------------------------------------
// Stage 1: fused split-K bf16-MFMA GEMM for both halves.
//   imgP[z][m][n]  = sum_{k in split z} img[m][k]  * W1[n][k]
//   attrP[z][m][n] = sum_{k in split z} attr[m][k] * W1[n][FEAT+k]
// BM=BN=64, BK=32, 4 waves/block; wave w owns m-rows [w*16, w*16+16).
// fp32 global -> (round+pack) bf16 LDS -> ds_read_b128 fragments -> MFMA.
// grid = (8 n-tiles, 2 img + 8 attr m-tiles, SPL) = 640 blocks.
// ---------------------------------------------------------------------------
constexpr int BM = 64, BN = 64, BK = 32;
constexpr int LDA = BK + 8;   // 40 shorts = 80 B row stride: 2-way banks (free)

__global__ __launch_bounds__(256) void gemm_bt_mfma(
    const float* __restrict__ img, const float* __restrict__ attr,
    const float* __restrict__ W1,
    float* __restrict__ imgP, float* __restrict__ attrP)
{
    __shared__ unsigned short As[BM * LDA];   // 5120 B
    __shared__ unsigned short Bs[BN * LDA];   // 5120 B

    const int t  = threadIdx.x;
    const int z  = blockIdx.z;
    const int n0 = blockIdx.x * BN;

    const float* A;
    float* P;
    int M, boff, m0;
    if (blockIdx.y < 2) {
        A = img;  P = imgP;  M = BATCH; boff = 0;
        m0 = blockIdx.y * BM;
    } else {
        A = attr; P = attrP; M = CLS;  boff = FEAT;
        m0 = (blockIdx.y - 2) * BM;
    }

    const int K   = FEAT;
    const int ldb = 2 * FEAT;
    const int Ks  = K / SPL;            // 128 -> 4 BK-chunks
    const int kb  = z * Ks;

    // staging role: thread t stages row t>>2 of both tiles, k-group (t&3)*8
    const int srow = t >> 2;            // 0..63
    const int skq  = (t & 3) * 8;       // 0,8,16,24

    const bool aok = (m0 + srow) < M;
    const float* Arow = A  + (size_t)(m0 + srow) * K  + kb;
    const float* Brow = W1 + (size_t)(n0 + srow) * ldb + boff + kb;

    // MFMA lane roles
    const int lane = t & 63;
    const int wid  = t >> 6;            // wave id 0..3 -> m-rows wid*16..+15
    const int ln   = lane & 15;
    const int quad = lane >> 4;         // 0..3

    f32x4 acc[4];
    #pragma unroll
    for (int nt = 0; nt < 4; ++nt) acc[nt] = (f32x4){0.f, 0.f, 0.f, 0.f};

    // prefetch chunk 0
    float4 a0, a1, b0, b1;
    a0 = aok ? *(const float4*)&Arow[skq]     : make_float4(0.f, 0.f, 0.f, 0.f);
    a1 = aok ? *(const float4*)&Arow[skq + 4] : make_float4(0.f, 0.f, 0.f, 0.f);
    b0 = *(const float4*)&Brow[skq];
    b1 = *(const float4*)&Brow[skq + 4];

    #pragma unroll
    for (int c = 0; c < 4; ++c) {       // 4 chunks of BK=32
        // pack prefetched fp32 -> bf16, commit to LDS (16B aligned)
        {
            uint4 pa = make_uint4(pkbf(a0.x, a0.y), pkbf(a0.z, a0.w),
                                  pkbf(a1.x, a1.y), pkbf(a1.z, a1.w));
            uint4 pb = make_uint4(pkbf(b0.x, b0.y), pkbf(b0.z, b0.w),
                                  pkbf(b1.x, b1.y), pkbf(b1.z, b1.w));
            *(uint4*)&As[srow * LDA + skq] = pa;
            *(uint4*)&Bs[srow * LDA + skq] = pb;
        }
        __syncthreads();

        // issue next chunk's global loads; latency hidden behind MFMA block
        if (c < 3) {
            const int ko = (c + 1) * BK + skq;
            a0 = aok ? *(const float4*)&Arow[ko]     : make_float4(0.f, 0.f, 0.f, 0.f);
            a1 = aok ? *(const float4*)&Arow[ko + 4] : make_float4(0.f, 0.f, 0.f, 0.f);
            b0 = *(const float4*)&Brow[ko];
            b1 = *(const float4*)&Brow[ko + 4];
        }

        // fragments: A row = wid*16+ln, B row = nt*16+ln, k = quad*8 + j
        const s16x8 af = *(const s16x8*)&As[(wid * 16 + ln) * LDA + quad * 8];
        #pragma unroll
        for (int nt = 0; nt < 4; ++nt) {
            const s16x8 bf = *(const s16x8*)&Bs[(nt * 16 + ln) * LDA + quad * 8];
            acc[nt] = __builtin_amdgcn_mfma_f32_16x16x32_bf16(af, bf, acc[nt], 0, 0, 0);
        }
        __syncthreads();
    }

    // epilogue: C[m][n], row m = m0 + wid*16 + quad*4 + r, col n = n0 + nt*16 + ln
    float* Pz = P + (size_t)z * M * HID;
    #pragma unroll
    for (int nt = 0; nt < 4; ++nt) {
        #pragma unroll
        for (int r = 0; r < 4; ++r) {
            const int m = m0 + wid * 16 + quad * 4 + r;
            if (m < M)
                Pz[(size_t)m * HID + n0 + nt * 16 + ln] = acc[nt][r];
        }
    }
}

// ---------------------------------------------------------------------------
// Stage 2: merge split-K partials; fold b1 into the image part.
// ---------------------------------------------------------------------------
__global__ __launch_bounds__(256) void merge_kernel(
    const float* __restrict__ imgP, const float* __restrict__ attrP,
    const float* __restrict__ b1,
    float* __restrict__ imgF, float* __restrict__ attrF)
{
    const int NIMG  = BATCH * HID;   // 65536
    const int NATTR = CLS * HID;     // 256000
    const int idx = blockIdx.x * 256 + threadIdx.x;
    if (idx < NIMG) {
        float s = 0.f;
        #pragma unroll
        for (int zz = 0; zz < SPL; ++zz) s += imgP[zz * NIMG + idx];
        imgF[idx] = s + b1[idx & (HID - 1)];
    } else if (idx < NIMG + NATTR) {
        const int j = idx - NIMG;
        float s = 0.f;
        #pragma unroll
        for (int zz = 0; zz < SPL; ++zz) s += attrP[zz * NATTR + j];
        attrF[j] = s;
    }
}

// ---------------------------------------------------------------------------
// Stage 3: out[b,c] = sigmoid( sum_h relu(u_b[h]+v_c[h]) * w2[h] + b2 )
// One wave per b-row (u, w2 wave-uniform -> scalar loads); 64 classes per
// block staged in LDS as [h4][class] float4 tiles with XOR swizzle.
// ---------------------------------------------------------------------------
constexpr int PC = 64;    // classes per block
constexpr int HC = 128;   // h chunk

__global__ __launch_bounds__(256) void pair_kernel(
    const float* __restrict__ imgF, const float* __restrict__ attrF,
    const float* __restrict__ W2, const float* __restrict__ b2,
    float* __restrict__ out)
{
    __shared__ float4 V[(HC / 4) * PC];   // 32 KB

    const int t   = threadIdx.x;
    const int ci  = t & 63;
    const int wid = __builtin_amdgcn_readfirstlane(t >> 6);  // wave id, SGPR
    const int b   = blockIdx.y * 4 + wid;                    // uniform per wave
    const int c0  = blockIdx.x * PC;

    const float* up = imgF + (size_t)b * HID;  // wave-uniform base -> s_load

    float ax = 0.f, ay = 0.f, az = 0.f, aw = 0.f;

    for (int hc = 0; hc < HID; hc += HC) {
        __syncthreads();
        #pragma unroll
        for (int rep = 0; rep < 8; ++rep) {
            const int idx = rep * 256 + t;    // 0..2047
            const int r   = idx >> 5;         // class row 0..63
            const int f4  = idx & 31;         // h-group 0..31
            float4 v = make_float4(0.f, 0.f, 0.f, 0.f);
            if (c0 + r < CLS)
                v = *(const float4*)&attrF[(size_t)(c0 + r) * HID + hc + f4 * 4];
            V[f4 * PC + ((r ^ f4) & 63)] = v;
        }
        __syncthreads();

        #pragma unroll
        for (int h4 = 0; h4 < HC / 4; ++h4) {
            const float4 v = V[h4 * PC + ((ci ^ h4) & 63)];
            const float4 u = *(const float4*)&up[hc + h4 * 4];  // scalar
            const float4 w = *(const float4*)&W2[hc + h4 * 4];  // scalar
            ax = fmaf(fmaxf(u.x + v.x, 0.f), w.x, ax);
            ay = fmaf(fmaxf(u.y + v.y, 0.f), w.y, ay);
            az = fmaf(fmaxf(u.z + v.z, 0.f), w.z, az);
            aw = fmaf(fmaxf(u.w + v.w, 0.f), w.w, aw);
        }
    }

    const int c = c0 + ci;
    if (c < CLS) {
        const float x = (ax + ay) + (az + aw) + b2[0];
        out[(size_t)b * CLS + c] = 1.f / (1.f + __expf(-x));
    }
}

// ---------------------------------------------------------------------------
extern "C" void kernel_launch(void* const* d_in, const int* in_sizes, int n_in,
                              void* d_out, int out_size, void* d_ws, size_t ws_size,
                              hipStream_t stream) {
    const float* img  = (const float*)d_in[0];   // (128, 1024)
    const float* attr = (const float*)d_in[1];   // (500, 1024)
    const float* W1   = (const float*)d_in[2];   // (512, 2048)
    const float* b1   = (const float*)d_in[3];   // (512,)
    const float* W2   = (const float*)d_in[4];   // (1, 512)
    const float* b2   = (const float*)d_in[5];   // (1,)
    float* out = (float*)d_out;                  // (128, 500)

    float* ws    = (float*)d_ws;
    float* imgP  = ws;                                  // SPL*128*512
    float* attrP = imgP  + (size_t)SPL * BATCH * HID;   // SPL*500*512
    float* imgF  = attrP + (size_t)SPL * CLS * HID;     // 128*512
    float* attrF = imgF  + (size_t)BATCH * HID;         // 500*512

    // Stage 1: both GEMMs, bf16 MFMA, split-K=8 -> 8 x 10 x 8 = 640 blocks
    dim3 ggrid(HID / BN, 2 + 8, SPL);
    gemm_bt_mfma<<<ggrid, 256, 0, stream>>>(img, attr, W1, imgP, attrP);

    // Stage 2: merge partials (+b1 on img side)
    const int ntot = BATCH * HID + CLS * HID;           // 321536
    merge_kernel<<<(ntot + 255) / 256, 256, 0, stream>>>(imgP, attrP, b1, imgF, attrF);

    // Stage 3: pair reduction + sigmoid; (8 c-tiles, 32 b-tiles) = 256 blocks
    dim3 pgrid((CLS + PC - 1) / PC, BATCH / 4);
    pair_kernel<<<pgrid, 256, 0, stream>>>(imgF, attrF, W2, b2, out);
}